// Round 9
// baseline (194.587 us; speedup 1.0000x reference)
//
#include <hip/hip_runtime.h>

// VectorQuantizer: X [16384][128] f32, E [128][8192] f32
// out (f32 flat): quantized [16384*128], encodings [16384*8192], indices [16384], loss [1]
#define D 128
#define K 8192
#define N 16384
#define BM 64                 // rows per block
#define BN 256                // codebook cols per chunk
#define NCH (K / BN)          // 32
#define THREADS 512
#define CAND_CAP 2944
#define DELTA 0.5f
#define RMIN_INIT 0xFF800000u // fsort(+inf); NOT 0xFFFFFFFF (decodes to NaN)

typedef __attribute__((ext_vector_type(4))) float f32x4;
typedef __attribute__((ext_vector_type(16))) float f32x16;
typedef __attribute__((ext_vector_type(8))) short short8;

__device__ __forceinline__ unsigned short f2bf(float f) {
    unsigned int b = __float_as_uint(f);
    return (unsigned short)((b + 0x7FFFu + ((b >> 16) & 1u)) >> 16);
}
__device__ __forceinline__ unsigned int fsort(float f) {
    unsigned int b = __float_as_uint(f);
    return b ^ ((unsigned int)((int)b >> 31) | 0x80000000u);
}
__device__ __forceinline__ float funsort(unsigned int u) {
    return __uint_as_float((u & 0x80000000u) ? (u ^ 0x80000000u) : ~u);
}

// LDS-only barrier. Its "memory" clobber also PINS instruction order:
// prefetch loads stay above it, zero-fill stores below it -> loads are OLDER
// than stores, so the ds_write's vmcnt wait (for loads) leaves stores in
// flight (in-order vmcnt). R7 lesson: in-loop enorm loads (younger than the
// stores) forced a full store drain every chunk; this version has ZERO global
// loads in the compute phase (enorm folded into the MFMA via aug k-slots).
__device__ __forceinline__ void lds_barrier() {
    asm volatile("s_waitcnt lgkmcnt(0)" ::: "memory");
    __builtin_amdgcn_s_barrier();
}

// ---- prep: E -> bf16 transposed e1t[k][d], augt[k][8]={en_hi,en_lo,0...},
//      f32 transposed e2t[k][d], enorm ----
__global__ __launch_bounds__(256) void prep_kernel(const float* __restrict__ E,
        unsigned short* __restrict__ e1t, unsigned short* __restrict__ augt,
        float* __restrict__ e2t, float* __restrict__ enorm) {
    __shared__ float esum[8][32];
    const int t = threadIdx.x;
    const int kl = t & 31, dg = t >> 5;
    const int k = blockIdx.x * 32 + kl;
    float s = 0.f;
    __align__(16) unsigned short tmpb[16];
    __align__(16) float tmpf[16];
#pragma unroll
    for (int j = 0; j < 16; ++j) {
        float v = E[(size_t)(dg * 16 + j) * K + k];
        s += v * v;
        tmpb[j] = f2bf(v);
        tmpf[j] = v;
    }
    *(f32x4*)(e1t + (size_t)k * D + dg * 16) = *(const f32x4*)tmpb;
    *(f32x4*)(e1t + (size_t)k * D + dg * 16 + 8) = *(const f32x4*)(tmpb + 8);
    if (e2t) {
#pragma unroll
        for (int q = 0; q < 4; ++q)
            *(f32x4*)(e2t + (size_t)k * D + dg * 16 + 4 * q) = *(const f32x4*)(tmpf + 4 * q);
    }
    esum[dg][kl] = s;
    __syncthreads();
    if (t < 32) {
        float e = 0.f;
#pragma unroll
        for (int g = 0; g < 8; ++g) e += esum[g][t];
        const int kk = blockIdx.x * 32 + t;
        enorm[kk] = e;
        unsigned short hi = f2bf(e);
        float hif = __uint_as_float((unsigned int)hi << 16);
        unsigned short lo = f2bf(e - hif);
        __align__(16) unsigned short av[8] = {hi, lo, 0, 0, 0, 0, 0, 0};
        *(f32x4*)(augt + (size_t)kk * 8) = *(const f32x4*)av;
    }
}

// ---- main: one sweep (aug-MFMA d~ + wave-min-gated candidate capture +
//      fused one-hot zero-fill), then exact f32 verify, then all outputs ----
template<int E2T>
__global__ __launch_bounds__(THREADS, 2) void main_kernel(
        const float* __restrict__ X, const float* __restrict__ E,
        const unsigned short* __restrict__ e1t, const unsigned short* __restrict__ augt,
        const float* __restrict__ e2t, const float* __restrict__ enorm,
        float* __restrict__ out, float* __restrict__ partials) {
    __shared__ __align__(16) unsigned short b_s[2][BN * D];   // 128 KB, XOR-swizzled
    __shared__ __align__(16) unsigned short aug_s[2][BN * 8]; // 8 KB, linear
    __shared__ unsigned long long cand[CAND_CAP];             // 23 KB
    __shared__ unsigned long long best[BM];                   // 512 B
    __shared__ unsigned int rmin[BM];                         // 256 B
    __shared__ int candn;

    const int t = threadIdx.x;
    const int wid = t >> 6, l = t & 63;
    const int l31 = l & 31, lh = l >> 5;
    const int wm = wid >> 2, wn = wid & 3;
    const int rowbase = blockIdx.x * BM;

    float* qout = out;
    float* enc = out + (size_t)N * D;
    float* idxout = enc + (size_t)N * K;

    if (t < BM) { rmin[t] = RMIN_INIT; best[t] = ~0ull; }
    if (t == 0) candn = 0;

    // A fragments: bf16(-2x) for wave's 32 rows; aug slots are constant 1.0
    short8 afr[8];
    {
        const int row = rowbase + wm * 32 + l31;
#pragma unroll
        for (int ks = 0; ks < 8; ++ks) {
            const float* xp = X + (size_t)row * D + ks * 16 + lh * 8;
            f32x4 v0 = *(const f32x4*)xp;
            f32x4 v1 = *(const f32x4*)(xp + 4);
            short8 a;
            a[0] = (short)f2bf(-2.f * v0[0]); a[1] = (short)f2bf(-2.f * v0[1]);
            a[2] = (short)f2bf(-2.f * v0[2]); a[3] = (short)f2bf(-2.f * v0[3]);
            a[4] = (short)f2bf(-2.f * v1[0]); a[5] = (short)f2bf(-2.f * v1[1]);
            a[6] = (short)f2bf(-2.f * v1[2]); a[7] = (short)f2bf(-2.f * v1[3]);
            afr[ks] = a;
        }
    }
    short8 a_aug;
    {
        const short one = (short)0x3F80;  // bf16 1.0
        a_aug[0] = (lh == 0) ? one : (short)0;
        a_aug[1] = (lh == 0) ? one : (short)0;
        a_aug[2] = 0; a_aug[3] = 0; a_aug[4] = 0;
        a_aug[5] = 0; a_aug[6] = 0; a_aug[7] = 0;
    }

    f32x4 sreg[8];
    f32x4 avreg;
    {   // prologue: stage chunk 0 into buf 0
        const f32x4* gs = (const f32x4*)e1t;
#pragma unroll
        for (int i = 0; i < 8; ++i) sreg[i] = gs[t + THREADS * i];
        if (t < 256) avreg = *(const f32x4*)(augt + (size_t)t * 8);
#pragma unroll
        for (int i = 0; i < 8; ++i) {
            int unit = t + THREADS * i;
            int c = unit >> 4, slot = unit & 15;
            *(f32x4*)((char*)&b_s[0][0] + c * 256 + ((slot ^ (c & 15)) << 4)) = sreg[i];
        }
        if (t < 256) *(f32x4*)((char*)&aug_s[0][0] + t * 16) = avreg;
    }

    int cur = 0;
    for (int ch = 0; ch < NCH; ++ch) {
        if (ch + 1 < NCH) {   // prefetch loads: pinned ABOVE barrier -> older than stores
            const f32x4* gs = (const f32x4*)(e1t + (size_t)(ch + 1) * BN * D);
#pragma unroll
            for (int i = 0; i < 8; ++i) sreg[i] = gs[t + THREADS * i];
            if (t < 256) avreg = *(const f32x4*)(augt + (size_t)(ch + 1) * BN * 8 + t * 8);
        }
        lds_barrier();   // buf[cur]+aug[cur] ready; prev rmin visible

        const int chcol = ch * BN;

        // fused one-hot zero-fill (nontemporal, stays in flight ~1 chunk)
        {
            const f32x4 z = {0.f, 0.f, 0.f, 0.f};
#pragma unroll
            for (int i = 0; i < 8; ++i) {
                int unit = t + THREADS * i;
                int row = unit >> 6, cu = unit & 63;
                __builtin_nontemporal_store(z,
                    (f32x4*)(enc + (size_t)(rowbase + row) * K + chcol + cu * 4));
            }
        }

        // per-row threshold cache (stale-safe: any observed value >= final)
        float thrv[16];
#pragma unroll
        for (int q = 0; q < 4; ++q) {
            const int base = wm * 32 + 4 * lh + 8 * q;
            uint4 rv = *(const uint4*)&rmin[base];
            thrv[4 * q + 0] = funsort(rv.x);
            thrv[4 * q + 1] = funsort(rv.y);
            thrv[4 * q + 2] = funsort(rv.z);
            thrv[4 * q + 3] = funsort(rv.w);
        }

        f32x16 acc[2];
#pragma unroll
        for (int nf = 0; nf < 2; ++nf)
#pragma unroll
            for (int r = 0; r < 16; ++r) acc[nf][r] = 0.f;

#pragma unroll
        for (int ks = 0; ks < 8; ++ks) {
            short8 bf[2];
#pragma unroll
            for (int nf = 0; nf < 2; ++nf) {
                int c = wn * 64 + nf * 32 + l31;
                int slot = ks * 2 + lh;
                bf[nf] = *(const short8*)((const char*)&b_s[cur][0] + c * 256 + ((slot ^ (c & 15)) << 4));
            }
#pragma unroll
            for (int nf = 0; nf < 2; ++nf)
                acc[nf] = __builtin_amdgcn_mfma_f32_32x32x16_bf16(afr[ks], bf[nf], acc[nf], 0, 0, 0);
        }
        // aug step: adds en (split into 2 bf16) -> acc becomes d~ = en - 2*sim
#pragma unroll
        for (int nf = 0; nf < 2; ++nf) {
            const int c = wn * 64 + nf * 32 + l31;
            short8 ba = {0, 0, 0, 0, 0, 0, 0, 0};
            if (lh == 0) ba = *(const short8*)((const char*)&aug_s[cur][0] + c * 16);
            acc[nf] = __builtin_amdgcn_mfma_f32_32x32x16_bf16(a_aug, ba, acc[nf], 0, 0, 0);
        }

        // wave-level per-row-slot min over this chunk's 64 cols
        float cmin[16];
#pragma unroll
        for (int r = 0; r < 16; ++r) cmin[r] = fminf(acc[0][r], acc[1][r]);
#pragma unroll
        for (int m = 1; m <= 16; m <<= 1)
#pragma unroll
            for (int r = 0; r < 16; ++r)
                cmin[r] = fminf(cmin[r], __shfl_xor(cmin[r], m, 64));

#pragma unroll
        for (int r = 0; r < 16; ++r) {
            const int ro = wm * 32 + 4 * lh + 8 * (r >> 2) + (r & 3);
            const float te = fminf(thrv[r], cmin[r]) + DELTA;
#pragma unroll
            for (int nf = 0; nf < 2; ++nf) {
                if (acc[nf][r] < te) {
                    const int col = chcol + wn * 64 + nf * 32 + l31;
                    int ci = atomicAdd(&candn, 1);
                    if (ci < CAND_CAP)
                        cand[ci] = ((unsigned long long)fsort(acc[nf][r]) << 32) |
                                   ((unsigned long long)ro << 13) | (unsigned)col;
                }
            }
            if (l31 == 0 && cmin[r] < thrv[r])
                atomicMin(&rmin[ro], fsort(cmin[r]));
        }

        if (ch + 1 < NCH) {  // ds_write waits only the (older) loads: vmcnt leaves stores flying
#pragma unroll
            for (int i = 0; i < 8; ++i) {
                int unit = t + THREADS * i;
                int c = unit >> 4, slot = unit & 15;
                *(f32x4*)((char*)&b_s[cur ^ 1][0] + c * 256 + ((slot ^ (c & 15)) << 4)) = sreg[i];
            }
            if (t < 256) *(f32x4*)((char*)&aug_s[cur ^ 1][0] + t * 16) = avreg;
        }
        cur ^= 1;
    }

    __syncthreads();   // FULL drain: zero-fill stores complete; rmin/cand final

    // ---- exact f32 verification of surviving candidates ----
    {
        int n = candn; if (n > CAND_CAP) n = CAND_CAP;
        for (int i = wid; i < n; i += 8) {     // one wave per candidate
            const unsigned long long e = cand[i];
            const float dta = funsort((unsigned int)(e >> 32));
            const int ro = (int)((e >> 13) & 63u);
            const int col = (int)(e & 8191u);
            if (dta < funsort(rmin[ro]) + DELTA) {
                const int row = rowbase + ro;
                float x0 = X[(size_t)row * D + l];
                float x1 = X[(size_t)row * D + 64 + l];
                float e0, e1;
                if (E2T) {
                    e0 = e2t[(size_t)col * D + l];
                    e1 = e2t[(size_t)col * D + 64 + l];
                } else {
                    e0 = E[(size_t)l * K + col];
                    e1 = E[(size_t)(l + 64) * K + col];
                }
                float s = x0 * e0 + x1 * e1;
#pragma unroll
                for (int m = 1; m <= 32; m <<= 1) s += __shfl_xor(s, m, 64);
                if (l == 0) {
                    float dtx = enorm[col] - 2.f * s;
                    atomicMin(&best[ro],
                        ((unsigned long long)fsort(dtx) << 32) | (unsigned)col);
                }
            }
        }
    }
    __syncthreads();

    // ---- outputs: indices, one-hot scatter, quantized, loss partial ----
    float* red = (float*)&b_s[0][0];   // b_s dead after loop
    if (t < BM) {
        const int k = (int)(best[t] & 8191ull);
        idxout[rowbase + t] = (float)k;
        __builtin_nontemporal_store(1.0f, &enc[(size_t)(rowbase + t) * K + k]);
    }

    const int rr = t >> 3, sL = t & 7;
    const int row = rowbase + rr;
    const int kb = (int)(best[rr] & 8191ull);
    float part = 0.f;
#pragma unroll
    for (int j = 0; j < 4; ++j) {
        const int d0 = sL * 16 + 4 * j;
        f32x4 xv = *(const f32x4*)(X + (size_t)row * D + d0);
        f32x4 ev;
        if (E2T) {
            ev = *(const f32x4*)(e2t + (size_t)kb * D + d0);
        } else {
#pragma unroll
            for (int u = 0; u < 4; ++u) ev[u] = E[(size_t)(d0 + u) * K + kb];
        }
        f32x4 qv;
#pragma unroll
        for (int u = 0; u < 4; ++u) {
            float df = ev[u] - xv[u];
            qv[u] = xv[u] + df;
            part += df * df;
        }
        *(f32x4*)(qout + (size_t)row * D + d0) = qv;
    }
    red[t] = part;
    __syncthreads();
#pragma unroll
    for (int off = THREADS / 2; off > 0; off >>= 1) {
        if (t < off) red[t] += red[t + off];
        __syncthreads();
    }
    if (t == 0) partials[blockIdx.x] = red[0];
}

__global__ __launch_bounds__(256) void loss_kernel(const float* __restrict__ partials,
                                                   float* __restrict__ out) {
    __shared__ float red[256];
    const int t = threadIdx.x;
    red[t] = partials[t];
    __syncthreads();
    for (int off = 128; off > 0; off >>= 1) {
        if (t < off) red[t] += red[t + off];
        __syncthreads();
    }
    if (t == 0) {
        float mean = red[0] / (float)((size_t)N * D);
        out[(size_t)N * D + (size_t)N * K + N] = mean + 0.25f * mean;
    }
}

extern "C" void kernel_launch(void* const* d_in, const int* in_sizes, int n_in,
                              void* d_out, int out_size, void* d_ws, size_t ws_size,
                              hipStream_t stream) {
    const float* X = (const float*)d_in[0];
    const float* E = (const float*)d_in[1];
    float* out = (float*)d_out;
    char* ws = (char*)d_ws;

    const size_t E1T_B = (size_t)K * D * 2;          // 2 MB
    const size_t AUG_B = (size_t)K * 8 * 2;          // 128 KB
    const size_t E2T_B = (size_t)K * D * 4;          // 4 MB
    const bool use_e2t = ws_size >= E1T_B + AUG_B + E2T_B + 64 * 1024;

    unsigned short* e1t = (unsigned short*)ws;
    unsigned short* augt = (unsigned short*)(ws + E1T_B);
    float* e2t; float* enorm; float* partials;
    if (use_e2t) {
        e2t = (float*)(ws + E1T_B + AUG_B);
        enorm = (float*)(ws + E1T_B + AUG_B + E2T_B);
        partials = enorm + K;
    } else {
        e2t = nullptr;
        enorm = (float*)(ws + E1T_B + AUG_B);
        partials = enorm + K;
    }

    hipLaunchKernelGGL(prep_kernel, dim3(K / 32), dim3(256), 0, stream,
                       E, e1t, augt, e2t, enorm);
    if (use_e2t)
        hipLaunchKernelGGL((main_kernel<1>), dim3(N / BM), dim3(THREADS), 0, stream,
                           X, E, e1t, augt, e2t, enorm, out, partials);
    else
        hipLaunchKernelGGL((main_kernel<0>), dim3(N / BM), dim3(THREADS), 0, stream,
                           X, E, e1t, augt, e2t, enorm, out, partials);
    hipLaunchKernelGGL(loss_kernel, dim3(1), dim3(256), 0, stream, partials, out);
}

// Round 10
// 173.143 us; speedup vs baseline: 1.1239x; 1.1239x over previous
//
#include <hip/hip_runtime.h>

// VectorQuantizer: X [16384][128] f32, E [128][8192] f32
// out (f32 flat): quantized [16384*128], encodings [16384*8192], indices [16384], loss [1]
#define D 128
#define K 8192
#define N 16384
#define BM 32                 // rows per block (grid 512 -> 2 blocks/CU)
#define BN 128                // codebook cols per chunk
#define NCH (K / BN)          // 64
#define GRP 4                 // chunks per gate-group (shuffle reduce 1x per group)
#define THREADS 256
#define CAND_CAP 1024
#define DELTA 0.5f
#define RMIN_INIT 0xFF800000u // fsort(+inf); NOT 0xFFFFFFFF (decodes to NaN)

typedef __attribute__((ext_vector_type(4))) float f32x4;
typedef __attribute__((ext_vector_type(16))) float f32x16;
typedef __attribute__((ext_vector_type(8))) short short8;

__device__ __forceinline__ unsigned short f2bf(float f) {
    unsigned int b = __float_as_uint(f);
    return (unsigned short)((b + 0x7FFFu + ((b >> 16) & 1u)) >> 16);
}
__device__ __forceinline__ unsigned int fsort(float f) {
    unsigned int b = __float_as_uint(f);
    return b ^ ((unsigned int)((int)b >> 31) | 0x80000000u);
}
__device__ __forceinline__ float funsort(unsigned int u) {
    return __uint_as_float((u & 0x80000000u) ? (u ^ 0x80000000u) : ~u);
}

// LDS-only barrier (lgkmcnt covers ds_read/ds_write/LDS-atomics; global
// stores/loads stay in flight). Cross-chunk store overlap now comes from the
// SECOND resident block per CU (desynced phases), not from wait gymnastics.
__device__ __forceinline__ void lds_barrier() {
    asm volatile("s_waitcnt lgkmcnt(0)" ::: "memory");
    __builtin_amdgcn_s_barrier();
}

// ---- prep: E -> bf16 transposed e1t[k][d], augt[k][8]={en_hi,en_lo,0...},
//      f32 transposed e2t[k][d], enorm ----
__global__ __launch_bounds__(256) void prep_kernel(const float* __restrict__ E,
        unsigned short* __restrict__ e1t, unsigned short* __restrict__ augt,
        float* __restrict__ e2t, float* __restrict__ enorm) {
    __shared__ float esum[8][32];
    const int t = threadIdx.x;
    const int kl = t & 31, dg = t >> 5;
    const int k = blockIdx.x * 32 + kl;
    float s = 0.f;
    __align__(16) unsigned short tmpb[16];
    __align__(16) float tmpf[16];
#pragma unroll
    for (int j = 0; j < 16; ++j) {
        float v = E[(size_t)(dg * 16 + j) * K + k];
        s += v * v;
        tmpb[j] = f2bf(v);
        tmpf[j] = v;
    }
    *(f32x4*)(e1t + (size_t)k * D + dg * 16) = *(const f32x4*)tmpb;
    *(f32x4*)(e1t + (size_t)k * D + dg * 16 + 8) = *(const f32x4*)(tmpb + 8);
    if (e2t) {
#pragma unroll
        for (int q = 0; q < 4; ++q)
            *(f32x4*)(e2t + (size_t)k * D + dg * 16 + 4 * q) = *(const f32x4*)(tmpf + 4 * q);
    }
    esum[dg][kl] = s;
    __syncthreads();
    if (t < 32) {
        float e = 0.f;
#pragma unroll
        for (int g = 0; g < 8; ++g) e += esum[g][t];
        const int kk = blockIdx.x * 32 + t;
        enorm[kk] = e;
        unsigned short hi = f2bf(e);
        float hif = __uint_as_float((unsigned int)hi << 16);
        unsigned short lo = f2bf(e - hif);
        __align__(16) unsigned short av[8] = {hi, lo, 0, 0, 0, 0, 0, 0};
        *(f32x4*)(augt + (size_t)kk * 8) = *(const f32x4*)av;
    }
}

// ---- main: one sweep, 4-chunk groups: {stage | zero-fill | aug-MFMA, d~ saved
//      in regs} x4, then ONE shuffle-min + gate + pushes per group.
//      Then exact f32 verify of candidates, then all outputs. ----
template<int E2T>
__global__ __launch_bounds__(THREADS, 2) void main_kernel(
        const float* __restrict__ X, const float* __restrict__ E,
        const unsigned short* __restrict__ e1t, const unsigned short* __restrict__ augt,
        const float* __restrict__ e2t, const float* __restrict__ enorm,
        float* __restrict__ out, float* __restrict__ partials) {
    __shared__ __align__(16) unsigned short b_s[2][BN * D];   // 64 KB, XOR-swizzled
    __shared__ __align__(16) unsigned short aug_s[2][BN * 8]; // 4 KB
    __shared__ unsigned long long cand[CAND_CAP];             // 8 KB
    __shared__ unsigned long long best[BM];                   // 256 B
    __shared__ unsigned int rmin[BM];                         // 128 B
    __shared__ int candn;
    // total ~78.2 KB -> 2 blocks/CU

    const int t = threadIdx.x;
    const int wid = t >> 6, l = t & 63;
    const int l31 = l & 31, lh = l >> 5;
    const int wn = wid;                 // 4 waves, one 32x32 tile each (cols wn*32)
    const int rowbase = blockIdx.x * BM;

    float* qout = out;
    float* enc = out + (size_t)N * D;
    float* idxout = enc + (size_t)N * K;

    if (t < BM) { rmin[t] = RMIN_INIT; best[t] = ~0ull; }
    if (t == 0) candn = 0;

    // A fragments: bf16(-2x), all 4 waves carry the block's 32 rows
    short8 afr[8];
    {
        const int row = rowbase + l31;
#pragma unroll
        for (int ks = 0; ks < 8; ++ks) {
            const float* xp = X + (size_t)row * D + ks * 16 + lh * 8;
            f32x4 v0 = *(const f32x4*)xp;
            f32x4 v1 = *(const f32x4*)(xp + 4);
            short8 a;
            a[0] = (short)f2bf(-2.f * v0[0]); a[1] = (short)f2bf(-2.f * v0[1]);
            a[2] = (short)f2bf(-2.f * v0[2]); a[3] = (short)f2bf(-2.f * v0[3]);
            a[4] = (short)f2bf(-2.f * v1[0]); a[5] = (short)f2bf(-2.f * v1[1]);
            a[6] = (short)f2bf(-2.f * v1[2]); a[7] = (short)f2bf(-2.f * v1[3]);
            afr[ks] = a;
        }
    }
    short8 a_aug;
    {
        const short one = (short)0x3F80;  // bf16 1.0
        a_aug[0] = (lh == 0) ? one : (short)0;
        a_aug[1] = (lh == 0) ? one : (short)0;
        a_aug[2] = 0; a_aug[3] = 0; a_aug[4] = 0;
        a_aug[5] = 0; a_aug[6] = 0; a_aug[7] = 0;
    }

    f32x4 sreg[8];
    f32x4 avreg;
    {   // prologue: stage chunk 0 into buf 0 (32 KB B + 2 KB aug)
        const f32x4* gs = (const f32x4*)e1t;
#pragma unroll
        for (int i = 0; i < 8; ++i) sreg[i] = gs[t + THREADS * i];
        if (t < 128) avreg = *(const f32x4*)(augt + (size_t)t * 8);
#pragma unroll
        for (int i = 0; i < 8; ++i) {
            int unit = t + THREADS * i;
            int c = unit >> 4, slot = unit & 15;
            *(f32x4*)((char*)&b_s[0][0] + c * 256 + ((slot ^ (c & 15)) << 4)) = sreg[i];
        }
        if (t < 128) *(f32x4*)((char*)&aug_s[0][0] + t * 16) = avreg;
    }

    int cur = 0;
    for (int cg = 0; cg < NCH / GRP; ++cg) {
        float dsave[GRP][16];   // compile-time indexed (unrolled) -> registers
#pragma unroll
        for (int g = 0; g < GRP; ++g) {
            const int ch = cg * GRP + g;
            if (ch + 1 < NCH) {
                const f32x4* gs = (const f32x4*)(e1t + (size_t)(ch + 1) * BN * D);
#pragma unroll
                for (int i = 0; i < 8; ++i) sreg[i] = gs[t + THREADS * i];
                if (t < 128) avreg = *(const f32x4*)(augt + (size_t)(ch + 1) * BN * 8 + t * 8);
            }
            lds_barrier();   // buf[cur] ready; stores stay in flight

            // fused one-hot zero-fill: 32 rows x 128 cols (nontemporal)
            {
                const f32x4 z = {0.f, 0.f, 0.f, 0.f};
#pragma unroll
                for (int i = 0; i < 4; ++i) {
                    int unit = t + THREADS * i;
                    int row = unit >> 5, cu = unit & 31;
                    __builtin_nontemporal_store(z,
                        (f32x4*)(enc + (size_t)(rowbase + row) * K + ch * BN + cu * 4));
                }
            }

            f32x16 acc;
#pragma unroll
            for (int r = 0; r < 16; ++r) acc[r] = 0.f;
#pragma unroll
            for (int ks = 0; ks < 8; ++ks) {
                const int c = wn * 32 + l31;
                const int slot = ks * 2 + lh;
                short8 bf = *(const short8*)((const char*)&b_s[cur][0] + c * 256 +
                                             ((slot ^ (c & 15)) << 4));
                acc = __builtin_amdgcn_mfma_f32_32x32x16_bf16(afr[ks], bf, acc, 0, 0, 0);
            }
            {   // aug: += en (2-way bf16 split) -> acc = d~ = en - 2*sim
                const int c = wn * 32 + l31;
                short8 ba = {0, 0, 0, 0, 0, 0, 0, 0};
                if (lh == 0) ba = *(const short8*)((const char*)&aug_s[cur][0] + c * 16);
                acc = __builtin_amdgcn_mfma_f32_32x32x16_bf16(a_aug, ba, acc, 0, 0, 0);
            }
#pragma unroll
            for (int r = 0; r < 16; ++r) dsave[g][r] = acc[r];

            if (ch + 1 < NCH) {
#pragma unroll
                for (int i = 0; i < 8; ++i) {
                    int unit = t + THREADS * i;
                    int c = unit >> 4, slot = unit & 15;
                    *(f32x4*)((char*)&b_s[cur ^ 1][0] + c * 256 + ((slot ^ (c & 15)) << 4)) = sreg[i];
                }
                if (t < 128) *(f32x4*)((char*)&aug_s[cur ^ 1][0] + t * 16) = avreg;
            }
            cur ^= 1;
        }

        // ---- per-group gate: ONE shuffle reduce per 4 chunks ----
        float lmin[16];
#pragma unroll
        for (int r = 0; r < 16; ++r)
            lmin[r] = fminf(fminf(dsave[0][r], dsave[1][r]),
                            fminf(dsave[2][r], dsave[3][r]));
#pragma unroll
        for (int m = 1; m <= 16; m <<= 1)
#pragma unroll
            for (int r = 0; r < 16; ++r)
                lmin[r] = fminf(lmin[r], __shfl_xor(lmin[r], m, 64));

        float thrv[16];
#pragma unroll
        for (int q = 0; q < 4; ++q) {
            const int base = 8 * q + 4 * lh;
            uint4 rv = *(const uint4*)&rmin[base];
            thrv[4 * q + 0] = funsort(rv.x);
            thrv[4 * q + 1] = funsort(rv.y);
            thrv[4 * q + 2] = funsort(rv.z);
            thrv[4 * q + 3] = funsort(rv.w);
        }

#pragma unroll
        for (int r = 0; r < 16; ++r) {
            const int ro = (r & 3) + 8 * (r >> 2) + 4 * lh;
            const float te = fminf(thrv[r], lmin[r]) + DELTA;
#pragma unroll
            for (int g = 0; g < GRP; ++g) {
                if (dsave[g][r] < te) {
                    const int col = (cg * GRP + g) * BN + wn * 32 + l31;
                    int ci = atomicAdd(&candn, 1);
                    if (ci < CAND_CAP)
                        cand[ci] = ((unsigned long long)fsort(dsave[g][r]) << 32) |
                                   ((unsigned long long)ro << 13) | (unsigned)col;
                }
            }
            if (l31 == 0 && lmin[r] < thrv[r])
                atomicMin(&rmin[ro], fsort(lmin[r]));
        }
    }

    __syncthreads();   // FULL drain: zero-fill stores complete; rmin/cand final

    // ---- exact f32 verification of surviving candidates ----
    {
        int n = candn; if (n > CAND_CAP) n = CAND_CAP;
        for (int i = wid; i < n; i += 4) {     // one wave per candidate
            const unsigned long long e = cand[i];
            const float dta = funsort((unsigned int)(e >> 32));
            const int ro = (int)((e >> 13) & 63u);
            const int col = (int)(e & 8191u);
            if (dta < funsort(rmin[ro]) + DELTA) {
                const int row = rowbase + ro;
                float x0 = X[(size_t)row * D + l];
                float x1 = X[(size_t)row * D + 64 + l];
                float e0, e1;
                if (E2T) {
                    e0 = e2t[(size_t)col * D + l];
                    e1 = e2t[(size_t)col * D + 64 + l];
                } else {
                    e0 = E[(size_t)l * K + col];
                    e1 = E[(size_t)(l + 64) * K + col];
                }
                float s = x0 * e0 + x1 * e1;
#pragma unroll
                for (int m = 1; m <= 32; m <<= 1) s += __shfl_xor(s, m, 64);
                if (l == 0) {
                    float dtx = enorm[col] - 2.f * s;
                    atomicMin(&best[ro],
                        ((unsigned long long)fsort(dtx) << 32) | (unsigned)col);
                }
            }
        }
    }
    __syncthreads();

    // ---- outputs: indices, one-hot scatter, quantized, loss partial ----
    float* red = (float*)&b_s[0][0];   // b_s dead after loop
    if (t < BM) {
        const int k = (int)(best[t] & 8191ull);
        idxout[rowbase + t] = (float)k;
        __builtin_nontemporal_store(1.0f, &enc[(size_t)(rowbase + t) * K + k]);
    }

    const int rr = t >> 3, sL = t & 7;
    const int row = rowbase + rr;
    const int kb = (int)(best[rr] & 8191ull);
    float part = 0.f;
#pragma unroll
    for (int j = 0; j < 4; ++j) {
        const int d0 = sL * 16 + 4 * j;
        f32x4 xv = *(const f32x4*)(X + (size_t)row * D + d0);
        f32x4 ev;
        if (E2T) {
            ev = *(const f32x4*)(e2t + (size_t)kb * D + d0);
        } else {
#pragma unroll
            for (int u = 0; u < 4; ++u) ev[u] = E[(size_t)(d0 + u) * K + kb];
        }
        f32x4 qv;
#pragma unroll
        for (int u = 0; u < 4; ++u) {
            float df = ev[u] - xv[u];
            qv[u] = xv[u] + df;
            part += df * df;
        }
        *(f32x4*)(qout + (size_t)row * D + d0) = qv;
    }
    red[t] = part;
    __syncthreads();
#pragma unroll
    for (int off = THREADS / 2; off > 0; off >>= 1) {
        if (t < off) red[t] += red[t + off];
        __syncthreads();
    }
    if (t == 0) partials[blockIdx.x] = red[0];
}

__global__ __launch_bounds__(256) void loss_kernel(const float* __restrict__ partials,
                                                   float* __restrict__ out) {
    __shared__ float red[256];
    const int t = threadIdx.x;
    red[t] = partials[t] + partials[t + 256];
    __syncthreads();
    for (int off = 128; off > 0; off >>= 1) {
        if (t < off) red[t] += red[t + off];
        __syncthreads();
    }
    if (t == 0) {
        float mean = red[0] / (float)((size_t)N * D);
        out[(size_t)N * D + (size_t)N * K + N] = mean + 0.25f * mean;
    }
}

extern "C" void kernel_launch(void* const* d_in, const int* in_sizes, int n_in,
                              void* d_out, int out_size, void* d_ws, size_t ws_size,
                              hipStream_t stream) {
    const float* X = (const float*)d_in[0];
    const float* E = (const float*)d_in[1];
    float* out = (float*)d_out;
    char* ws = (char*)d_ws;

    const size_t E1T_B = (size_t)K * D * 2;          // 2 MB
    const size_t AUG_B = (size_t)K * 8 * 2;          // 128 KB
    const size_t E2T_B = (size_t)K * D * 4;          // 4 MB
    const bool use_e2t = ws_size >= E1T_B + AUG_B + E2T_B + 64 * 1024;

    unsigned short* e1t = (unsigned short*)ws;
    unsigned short* augt = (unsigned short*)(ws + E1T_B);
    float* e2t; float* enorm; float* partials;
    if (use_e2t) {
        e2t = (float*)(ws + E1T_B + AUG_B);
        enorm = (float*)(ws + E1T_B + AUG_B + E2T_B);
        partials = enorm + K;
    } else {
        e2t = nullptr;
        enorm = (float*)(ws + E1T_B + AUG_B);
        partials = enorm + K;
    }

    hipLaunchKernelGGL(prep_kernel, dim3(K / 32), dim3(256), 0, stream,
                       E, e1t, augt, e2t, enorm);
    if (use_e2t)
        hipLaunchKernelGGL((main_kernel<1>), dim3(N / BM), dim3(THREADS), 0, stream,
                           X, E, e1t, augt, e2t, enorm, out, partials);
    else
        hipLaunchKernelGGL((main_kernel<0>), dim3(N / BM), dim3(THREADS), 0, stream,
                           X, E, e1t, augt, e2t, enorm, out, partials);
    hipLaunchKernelGGL(loss_kernel, dim3(1), dim3(256), 0, stream, partials, out);
}